// Round 9
// baseline (221.116 us; speedup 1.0000x reference)
//
#include <hip/hip_runtime.h>
#include <math.h>

#define NH 16

typedef __bf16 bf16x8 __attribute__((ext_vector_type(8)));
typedef float f32x4 __attribute__((ext_vector_type(4)));

__device__ __forceinline__ unsigned short f2bf(float f) {
  unsigned u = __float_as_uint(f);
  u += 0x7fffu + ((u >> 16) & 1u);            // RNE (prep/epilogue paths only)
  return (unsigned short)(u >> 16);
}
__device__ __forceinline__ float bf2f(unsigned short h) {
  return __uint_as_float(((unsigned)h) << 16);
}
__device__ __forceinline__ float fexp2(float x) {
  return __builtin_amdgcn_exp2f(x);           // raw v_exp_f32 (2^x)
}
// Q is stored pre-scaled by 0.125*log2e. tanh(q) = 1 - 2/(2^(16*stored)+1).
__device__ __forceinline__ float fast_tanh16(float x) {
  return 1.f - 2.f * __builtin_amdgcn_rcpf(fexp2(16.f * x) + 1.f);
}
__device__ __forceinline__ void gl_lds16(const void* g, void* l) {
  __builtin_amdgcn_global_load_lds((const __attribute__((address_space(1))) void*)g,
                                   (__attribute__((address_space(3))) void*)l, 16, 0, 0);
}
union Frag8 { bf16x8 v; unsigned short u[8]; };
union FragU { bf16x8 v; unsigned u[4]; };

// ---------------------------------------------------------------------------
// prep_all: one launch for ALL input conversions (x, Wq/Wk/Wv, Wo split,
// and the lam*log2e*J^T transpose folded in as blocks 8192..8207).
// ---------------------------------------------------------------------------
__global__ __launch_bounds__(256) void prep_all(const float* __restrict__ x,
                                                const float* __restrict__ Wq,
                                                const float* __restrict__ Wk,
                                                const float* __restrict__ Wv,
                                                const float* __restrict__ Wo,
                                                const float* __restrict__ J,
                                                const float* __restrict__ lam_p,
                                                unsigned short* __restrict__ xh,
                                                unsigned short* __restrict__ wcat3,
                                                unsigned short* __restrict__ wocat,
                                                unsigned short* __restrict__ Jt)
{
  __shared__ float T[64][65];
  const int bid = blockIdx.x, tid = threadIdx.x;
  if (bid >= 8192) {
    // prep_jt: Jt[h][e][d] = bf16( lam * log2e * J[h][d][e] )
    const int h = bid - 8192;
    const float lam = lam_p[0] * 1.44269504f;
#pragma unroll
    for (int c = 0; c < 4; ++c) {
      int i = tid + c*256;
      int d = i >> 4, e4 = i & 15;
      float4 v = *(const float4*)&J[(size_t)h*4096 + d*64 + e4*4];
      T[d][e4*4+0] = v.x; T[d][e4*4+1] = v.y; T[d][e4*4+2] = v.z; T[d][e4*4+3] = v.w;
    }
    __syncthreads();
    const int e = tid >> 2, d0 = (tid & 3) * 16;
#pragma unroll
    for (int j4 = 0; j4 < 4; ++j4) {
      ushort4 o;
      o.x = f2bf(lam * T[d0+j4*4+0][e]);
      o.y = f2bf(lam * T[d0+j4*4+1][e]);
      o.z = f2bf(lam * T[d0+j4*4+2][e]);
      o.w = f2bf(lam * T[d0+j4*4+3][e]);
      *(ushort4*)&Jt[((size_t)h*64 + e)*64 + d0 + j4*4] = o;
    }
    return;
  }
  if (bid < 4096) {
    int i = bid * 256 + tid;
    float4 v = *(const float4*)&x[(size_t)i*4];
    ushort4 o;
    o.x = f2bf(v.x); o.y = f2bf(v.y); o.z = f2bf(v.z); o.w = f2bf(v.w);
    *(ushort4*)&xh[(size_t)i*4] = o;
  } else if (bid < 7168) {
    int i = (bid - 4096) * 256 + tid;
    int sel = i >> 18, loc = i & 262143;
    const float* src = (sel == 0) ? Wq : (sel == 1) ? Wk : Wv;
    float4 v = *(const float4*)&src[(size_t)loc*4];
    ushort4 o;
    o.x = f2bf(v.x); o.y = f2bf(v.y); o.z = f2bf(v.z); o.w = f2bf(v.w);
    *(ushort4*)&wcat3[(size_t)i*4] = o;
  } else {
    int i = (bid - 7168) * 256 + tid;
    int r = i >> 8, c = i & 255;
    float4 v = *(const float4*)&Wo[(size_t)r*1024 + c*4];
    ushort4 hi, lo;
    hi.x = f2bf(v.x); lo.x = f2bf(v.x - bf2f(hi.x));
    hi.y = f2bf(v.y); lo.y = f2bf(v.y - bf2f(hi.y));
    hi.z = f2bf(v.z); lo.z = f2bf(v.z - bf2f(hi.z));
    hi.w = f2bf(v.w); lo.w = f2bf(v.w - bf2f(hi.w));
    *(ushort4*)&wocat[(size_t)r*2048 + c*4]        = hi;
    *(ushort4*)&wocat[(size_t)r*2048 + 1024 + c*4] = lo;
  }
}

// ---------------------------------------------------------------------------
// gemm_qkv: merged Q/K/V projection, 1-term bf16, 128x128 tile, BK=64.
// 4-wave / 64x64-per-wave geometry, one-barrier issue-early double buffer.
// build_qj2 fused into the mode-0 epilogue. mode-2 stores Vt key-permuted
// (32-window order [0-3,16-19,4-7,20-23,...]) for flash8's single-b128 V read.
// ---------------------------------------------------------------------------
__global__ __launch_bounds__(256) void gemm_qkv(const unsigned short* __restrict__ A,
                                                const unsigned short* __restrict__ W,
                                                const float* __restrict__ bq,
                                                const float* __restrict__ bk,
                                                const float* __restrict__ bv,
                                                const unsigned short* __restrict__ Jt,
                                                unsigned short* __restrict__ Qcat,
                                                unsigned short* __restrict__ Kcat,
                                                unsigned short* __restrict__ Vt)
{
  __shared__ unsigned short S[32768];   // 2 buf x (A 8192 | W 8192) shorts
  const int tid = threadIdx.x, lane = tid & 63, wq = tid >> 6;
  const int l15 = lane & 15, lq = lane >> 4;
  const int n0 = blockIdx.x * 128, m0 = blockIdx.y * 128;
  const int wr = (wq & 1) * 64, wc = (wq >> 1) * 64;
  const int mode = n0 >> 10;

  f32x4 acc[4][4];
#pragma unroll
  for (int mb = 0; mb < 4; ++mb)
#pragma unroll
    for (int nb = 0; nb < 4; ++nb) { f32x4 z = {0.f,0.f,0.f,0.f}; acc[mb][nb] = z; }

  const unsigned short* mat = (wq < 2) ? A : W;
  const int rbase = (wq < 2) ? m0 : n0;
  const int srow = lane >> 3, sslot = lane & 7;

  auto STAGE = [&](int buf, int k0) {
    unsigned short* lb = S + buf*16384 + (wq >> 1) * 8192;
#pragma unroll
    for (int t = 0; t < 8; ++t) {
      int row = (wq & 1) * 64 + t*8 + srow;
      int chunk = sslot ^ (row & 7);
      gl_lds16(mat + (size_t)(rbase + row)*1024 + k0 + chunk*8,
               lb + ((wq & 1) * 64 + t*8) * 64);
    }
  };

  int cur = 0;
  STAGE(0, 0);
  __syncthreads();

  for (int k0 = 0; k0 < 1024; k0 += 64) {
    if (k0 + 64 < 1024) STAGE(cur ^ 1, k0 + 64);
    const unsigned short* Sc = S + cur*16384;
#pragma unroll
    for (int kk = 0; kk < 2; ++kk) {
      int c = kk*4 + lq;
      bf16x8 af[4], bf_[4];
#pragma unroll
      for (int mb = 0; mb < 4; ++mb) {
        int m = wr + mb*16 + l15;
        af[mb] = *(const bf16x8*)&Sc[m*64 + (c ^ (m & 7))*8];
      }
#pragma unroll
      for (int nb = 0; nb < 4; ++nb) {
        int n = wc + nb*16 + l15;
        bf_[nb] = *(const bf16x8*)&Sc[8192 + n*64 + (c ^ (n & 7))*8];
      }
#pragma unroll
      for (int mb = 0; mb < 4; ++mb)
#pragma unroll
        for (int nb = 0; nb < 4; ++nb)
          acc[mb][nb] = __builtin_amdgcn_mfma_f32_16x16x32_bf16(af[mb], bf_[nb], acc[mb][nb], 0,0,0);
    }
    __syncthreads();   // drains prefetch vmcnt AFTER compute
    cur ^= 1;
  }

  const float* bias = (mode == 0) ? bq : (mode == 1) ? bk : bv;
  float bvv[4];
#pragma unroll
  for (int nb = 0; nb < 4; ++nb) bvv[nb] = bias[((n0 & 1023) + wc + nb*16 + l15)];

  if (mode == 2) {
#pragma unroll
    for (int mb = 0; mb < 4; ++mb) {
      int mrow = m0 + wr + mb*16 + lq*4;
      int b = mrow >> 11, s0 = mrow & 2047;
      // key-window permutation: group g=(s0>>2)&7 -> position 2*(g&3)+(g>>2)
      int s0p = (s0 & ~31) + (((s0 >> 2) & 3) << 3) + (((s0 >> 4) & 1) << 2);
#pragma unroll
      for (int nb = 0; nb < 4; ++nb) {
        int n = (n0 & 1023) + wc + nb*16 + l15;
        int h = n >> 6, d = n & 63;
        ushort4 o;
        o.x = f2bf(acc[mb][nb][0] + bvv[nb]);
        o.y = f2bf(acc[mb][nb][1] + bvv[nb]);
        o.z = f2bf(acc[mb][nb][2] + bvv[nb]);
        o.w = f2bf(acc[mb][nb][3] + bvv[nb]);
        *(ushort4*)&Vt[((size_t)(b*NH + h)*64 + d)*2048 + s0p] = o;
      }
    }
    return;
  }

  if (mode == 1) {
#pragma unroll
    for (int mb = 0; mb < 4; ++mb) {
#pragma unroll
      for (int r = 0; r < 4; ++r) {
        int m = m0 + wr + mb*16 + lq*4 + r;
        int b = m >> 11, s = m & 2047;
#pragma unroll
        for (int nb = 0; nb < 4; ++nb) {
          float v = acc[mb][nb][r] + bvv[nb];
          int n = (n0 & 1023) + wc + nb*16 + l15;
          int h = n >> 6, d = n & 63;
          size_t row = ((size_t)(b*NH + h)*2048 + s)*128;
          Kcat[row + d]      = f2bf(v);
          Kcat[row + 64 + d] = f2bf(1.f - 2.f * __builtin_amdgcn_rcpf(__expf(2.f*v) + 1.f));
        }
      }
    }
    return;
  }

  // ---- mode 0: Q write + fused QJ (formerly build_qj2) ----
  unsigned short* T = S + wq * 4608;
#pragma unroll
  for (int mb = 0; mb < 4; ++mb) {
#pragma unroll
    for (int r = 0; r < 4; ++r) {
      int m = m0 + wr + mb*16 + lq*4 + r;
      int b = m >> 11, s = m & 2047;
#pragma unroll
      for (int nb = 0; nb < 4; ++nb) {
        float v = acc[mb][nb][r] + bvv[nb];
        int n = (n0 & 1023) + wc + nb*16 + l15;
        int h = n >> 6, d = n & 63;
        unsigned short qb = f2bf(v * 0.18033688f);   // 0.125 * log2(e)
        Qcat[((size_t)(b*NH + h)*2048 + s)*128 + d] = qb;
        T[(mb*16 + lq*4 + r)*72 + d] = qb;
      }
    }
  }
  const int h = ((n0 & 1023) + wc) >> 6;             // this wave's head
  bf16x8 jf2[4][2];
#pragma unroll
  for (int nb2 = 0; nb2 < 4; ++nb2)
#pragma unroll
    for (int kst = 0; kst < 2; ++kst)
      jf2[nb2][kst] = *(const bf16x8*)&Jt[((size_t)h*64 + nb2*16 + l15)*64 + kst*32 + lq*8];
#pragma unroll
  for (int mb = 0; mb < 4; ++mb) {
    Frag8 af2[2];
#pragma unroll
    for (int kst = 0; kst < 2; ++kst) {
      Frag8 raw;
      raw.v = *(const bf16x8*)&T[(mb*16 + l15)*72 + kst*32 + lq*8];
#pragma unroll
      for (int j = 0; j < 8; ++j) {
        float t = fast_tanh16(bf2f(raw.u[j]));
        af2[kst].u[j] = (unsigned short)(__float_as_uint(t) >> 16);  // trunc
      }
    }
    f32x4 a2[4];
#pragma unroll
    for (int nb2 = 0; nb2 < 4; ++nb2) { f32x4 z = {0.f,0.f,0.f,0.f}; a2[nb2] = z; }
#pragma unroll
    for (int kst = 0; kst < 2; ++kst)
#pragma unroll
      for (int nb2 = 0; nb2 < 4; ++nb2)
        a2[nb2] = __builtin_amdgcn_mfma_f32_16x16x32_bf16(af2[kst].v, jf2[nb2][kst], a2[nb2], 0,0,0);
    int mrow = m0 + wr + mb*16 + lq*4;
    int b = mrow >> 11, s0 = mrow & 2047;
#pragma unroll
    for (int r = 0; r < 4; ++r) {
      size_t rowb = ((size_t)(b*NH + h)*2048 + s0 + r)*128 + 64;
#pragma unroll
      for (int nb2 = 0; nb2 < 4; ++nb2)
        Qcat[rowb + nb2*16 + l15] = f2bf(a2[nb2][r]);
    }
  }
}

// ---------------------------------------------------------------------------
// flash8: S^T MFMA flash, NO split-K. grid 512 (32 bh x 16 row-tiles),
// 256 thr / 4 waves, dbuf.
// R9: counted-vmcnt schedule (T4). __syncthreads() compiles to
// `s_waitcnt vmcnt(0); s_barrier` — it drained the prefetch issued at loop
// top, exposing L2 latency every jt (R8: conflicts fixed, time unchanged ->
// latency-bound). Now: raw s_barrier + asm `s_waitcnt vmcnt(6)` — each STAGE
// is exactly 6 VMEM ops/wave (4 K + 2 V), so vmcnt(6) retires precisely the
// CURRENT buffer's loads while next-tile prefetch stays in flight across
// both barriers. sched_barrier(0) after the waitcnt (rule #18); "memory"
// clobber pins gl_lds issue order; vmcnt(0) on the last iteration.
// ---------------------------------------------------------------------------
__global__ __launch_bounds__(256, 4) void flash8(
    const unsigned short* __restrict__ Qcat, const unsigned short* __restrict__ Kcat,
    const unsigned short* __restrict__ Vt, unsigned short* __restrict__ attcat)
{
  __shared__ __align__(16) char smem[49152];
  unsigned short* Ks = (unsigned short*)smem;            // 2 x 64x128 bf16
  unsigned short* Vs = (unsigned short*)(smem + 32768);  // 2 x 64x64  bf16
  const int tid = threadIdx.x, lane = tid & 63, wq = tid >> 6;
  const int l15 = lane & 15, lq = lane >> 4;
  const int bid = blockIdx.x;
  // bid = xcd + 8*(bhi + 4*inner): same bh -> same XCD L2
  const int bh = (((bid >> 3) & 3) << 3) | (bid & 7);
  const int inner = bid >> 5;                  // 0..15
  const int row0 = inner * 128;

  Frag8 qf[2][4];
#pragma unroll
  for (int nb = 0; nb < 2; ++nb) {
    const unsigned short* qp = Qcat + ((size_t)(bh*2048 + row0 + wq*32 + nb*16 + l15))*128 + lq*8;
#pragma unroll
    for (int kst = 0; kst < 4; ++kst)
      qf[nb][kst].v = *(const bf16x8*)(qp + kst*32);
  }

  FragU ones;
  ones.u[0] = 0x3F803F80u; ones.u[1] = 0x3F803F80u;
  ones.u[2] = 0x3F803F80u; ones.u[3] = 0x3F803F80u;

  f32x4 o[4][2];
  f32x4 lacc[2];
  { f32x4 z = {0.f,0.f,0.f,0.f}; lacc[0] = z; lacc[1] = z; }
#pragma unroll
  for (int db = 0; db < 4; ++db)
#pragma unroll
    for (int nb = 0; nb < 2; ++nb) { f32x4 z = {0.f,0.f,0.f,0.f}; o[db][nb] = z; }

  const unsigned short* kgb = Kcat + ((size_t)bh*2048)*128;
  const unsigned short* vg  = Vt + (size_t)bh*64*2048;

  auto STAGE = [&](int buf, int jt) {
#pragma unroll
    for (int t = 0; t < 4; ++t) {
      int g = (wq*4 + t)*4 + (lane >> 4);
      int slot = lane & 15;
      int chunk = (slot & 8) | ((slot ^ g) & 7);
      gl_lds16(kgb + (size_t)(jt*64 + g)*128 + chunk*8, Ks + buf*8192 + (wq*4 + t)*512);
    }
#pragma unroll
    for (int t = 0; t < 2; ++t) {
      int rv = (wq*2 + t)*8 + (lane >> 3);
      int chunk = (lane & 7) ^ (rv & 7);
      gl_lds16(vg + (size_t)rv*2048 + jt*64 + chunk*8, Vs + buf*4096 + (wq*2 + t)*512);
    }
  };

  int cur = 0;
  STAGE(0, 0);

  for (int jt = 0; jt < 32; ++jt) {
    if (jt + 1 < 32) {
      STAGE(cur ^ 1, jt + 1);                          // 6 more VMEM in flight
      asm volatile("s_waitcnt vmcnt(6)" ::: "memory"); // current buffer ready
    } else {
      asm volatile("s_waitcnt vmcnt(0)" ::: "memory"); // last tile: drain all
    }
    __builtin_amdgcn_sched_barrier(0);
    __builtin_amdgcn_s_barrier();                      // all waves see buf[cur]

    const unsigned short* ksb = Ks + cur*8192;
    const unsigned short* vsb = Vs + cur*4096;

    // process keys in two half-tiles of 32: QK^T + exp then immediately PV,
    // so only 8 packed-P regs are live at a time.
#pragma unroll
    for (int t = 0; t < 2; ++t) {
      unsigned P2[2][2][2];
#pragma unroll
      for (int kk = 0; kk < 2; ++kk) {
        const int kb = 2*t + kk;
        bf16x8 af[4];
#pragma unroll
        for (int kst = 0; kst < 4; ++kst) {
          int key = kb*16 + l15;
          int c = kst*4 + lq;
          int slot = (c & 8) | ((c ^ key) & 7);
          af[kst] = *(const bf16x8*)&ksb[key*128 + slot*8];
        }
        f32x4 s[2];
        { f32x4 z = {0.f,0.f,0.f,0.f}; s[0] = z; s[1] = z; }
        __builtin_amdgcn_s_setprio(1);
#pragma unroll
        for (int kst = 0; kst < 4; ++kst) {
          s[0] = __builtin_amdgcn_mfma_f32_16x16x32_bf16(af[kst], qf[0][kst].v, s[0], 0,0,0);
          s[1] = __builtin_amdgcn_mfma_f32_16x16x32_bf16(af[kst], qf[1][kst].v, s[1], 0,0,0);
        }
        __builtin_amdgcn_s_setprio(0);
#pragma unroll
        for (int nb = 0; nb < 2; ++nb) {
          float e0 = fexp2(s[nb][0]), e1 = fexp2(s[nb][1]);
          float e2 = fexp2(s[nb][2]), e3 = fexp2(s[nb][3]);
          P2[nb][kk][0] = __builtin_amdgcn_perm(__float_as_uint(e1), __float_as_uint(e0), 0x07060302u);
          P2[nb][kk][1] = __builtin_amdgcn_perm(__float_as_uint(e3), __float_as_uint(e2), 0x07060302u);
        }
      }

      // PV for this half-tile (keys t*32 .. t*32+31)
      FragU bfr[2];
#pragma unroll
      for (int nb = 0; nb < 2; ++nb) {
        bfr[nb].u[0] = P2[nb][0][0];
        bfr[nb].u[1] = P2[nb][0][1];
        bfr[nb].u[2] = P2[nb][1][0];
        bfr[nb].u[3] = P2[nb][1][1];
      }
      __builtin_amdgcn_s_setprio(1);
      // row-sum of P over these 32 keys via ones-MFMA (D rows all = col sum)
      lacc[0] = __builtin_amdgcn_mfma_f32_16x16x32_bf16(ones.v, bfr[0].v, lacc[0], 0,0,0);
      lacc[1] = __builtin_amdgcn_mfma_f32_16x16x32_bf16(ones.v, bfr[1].v, lacc[1], 0,0,0);

#pragma unroll
      for (int db = 0; db < 4; ++db) {
        int d = db*16 + l15;
        Frag8 va;
        va.v = *(const bf16x8*)&vsb[d*64 + (((4*t + lq) ^ (d & 7)) * 8)];
        o[db][0] = __builtin_amdgcn_mfma_f32_16x16x32_bf16(va.v, bfr[0].v, o[db][0], 0,0,0);
        o[db][1] = __builtin_amdgcn_mfma_f32_16x16x32_bf16(va.v, bfr[1].v, o[db][1], 0,0,0);
      }
      __builtin_amdgcn_s_setprio(0);
    }

    __builtin_amdgcn_s_barrier();   // all waves done reading buf[cur];
    cur ^= 1;                       // prefetch (cur^1) still in flight
  }

  // epilogue: divide by denominator (lacc rows identical, per-lane by q=l15),
  // write attcat bf16 hi|lo directly, coalesced via LDS transpose (two halves
  // of 64 rows; Ts overlays the dead Ks/Vs).
  const int b = bh >> 4, h = bh & (NH-1);
  const float inv0 = 1.f / lacc[0][0];
  const float inv1 = 1.f / lacc[1][0];
  float* Ts = (float*)smem;                    // 64 x 65 f32 = 16.6KB
#pragma unroll
  for (int half = 0; half < 2; ++half) {
    __syncthreads();
    if ((wq >> 1) == half) {
#pragma unroll
      for (int nb = 0; nb < 2; ++nb) {
        const float inv = nb ? inv1 : inv0;
        const int rl = (wq & 1)*32 + nb*16 + l15;
#pragma unroll
        for (int db = 0; db < 4; ++db)
#pragma unroll
          for (int r = 0; r < 4; ++r)
            Ts[rl*65 + db*16 + lq*4 + r] = o[db][nb][r] * inv;
      }
    }
    __syncthreads();
    const int sl = tid >> 2, d0 = (tid & 3) * 16;
    const int srow = row0 + half*64 + sl;
    const size_t rb = ((size_t)(b*2048 + srow))*2048 + h*64;
#pragma unroll
    for (int j4 = 0; j4 < 4; ++j4) {
      float v0 = Ts[sl*65 + d0 + j4*4 + 0];
      float v1 = Ts[sl*65 + d0 + j4*4 + 1];
      float v2 = Ts[sl*65 + d0 + j4*4 + 2];
      float v3 = Ts[sl*65 + d0 + j4*4 + 3];
      ushort4 hi, lo;
      hi.x = f2bf(v0); lo.x = f2bf(v0 - bf2f(hi.x));
      hi.y = f2bf(v1); lo.y = f2bf(v1 - bf2f(hi.y));
      hi.z = f2bf(v2); lo.z = f2bf(v2 - bf2f(hi.z));
      hi.w = f2bf(v3); lo.w = f2bf(v3 - bf2f(hi.w));
      *(ushort4*)&attcat[rb + d0 + j4*4]        = hi;
      *(ushort4*)&attcat[rb + 1024 + d0 + j4*4] = lo;
    }
  }
}

// ---------------------------------------------------------------------------
// gemm3b: out = attn@Wo^T + bo, split-bf16 3-term.
// 128x128 tile, 8 waves (512 thr), grid (8,32) = 256 blocks = exactly 1/CU.
// Whole-CU LDS: 2 x 32KB double buffer; issue-early prefetch, one barrier
// per K-step (T3-minimum schedule).
// ---------------------------------------------------------------------------
__global__ __launch_bounds__(512) void gemm3b(const unsigned short* __restrict__ A,
                                              const unsigned short* __restrict__ W,
                                              const float* __restrict__ bias,
                                              float* __restrict__ out)
{
  __shared__ unsigned short S[65536];   // 2 buffers x 4 regions x 128x64
  const int tid = threadIdx.x, lane = tid & 63, wid = tid >> 6;
  const int l15 = lane & 15, lq = lane >> 4;
  const int n0 = blockIdx.x * 128, m0 = blockIdx.y * 128;
  const int wrow = wid >> 2, wcol = wid & 3;     // 2x4 wave grid, 64x32 each

  f32x4 acc[4][2];
#pragma unroll
  for (int mb = 0; mb < 4; ++mb)
#pragma unroll
    for (int nb = 0; nb < 2; ++nb) { f32x4 z = {0.f,0.f,0.f,0.f}; acc[mb][nb] = z; }

  // staging: region = wid>>1 (0=A-hi,1=A-lo,2=W-hi,3=W-lo), each wave 64 rows
  const int region = wid >> 1;
  const unsigned short* mat = (region < 2) ? A : W;
  const int rbase = (region < 2) ? m0 : n0;
  const int koff  = (region & 1) * 1024;
  const int rhalf = (wid & 1) * 64;
  const int srow = lane >> 3, sslot = lane & 7;

  auto STAGE = [&](int buf, int k0) {
    unsigned short* lb = S + buf*32768 + region*8192 + rhalf*64;
#pragma unroll
    for (int t = 0; t < 8; ++t) {
      int row = rhalf + t*8 + srow;
      int chunk = sslot ^ (row & 7);
      gl_lds16(mat + (size_t)(rbase + row)*2048 + koff + k0 + chunk*8,
               lb + t*512);
    }
  };

  int cur = 0;
  STAGE(0, 0);
  __syncthreads();

  for (int k0 = 0; k0 < 1024; k0 += 64) {
    if (k0 + 64 < 1024) STAGE(cur ^ 1, k0 + 64);
    const unsigned short* Sc = S + cur*32768;
#pragma unroll
    for (int kk = 0; kk < 2; ++kk) {
      int c = kk*4 + lq;
      bf16x8 ah[4], al[4], bh_[2], bl_[2];
#pragma unroll
      for (int mb = 0; mb < 4; ++mb) {
        int m = wrow*64 + mb*16 + l15;
        int so = (c ^ (m & 7))*8;
        ah[mb] = *(const bf16x8*)&Sc[m*64 + so];
        al[mb] = *(const bf16x8*)&Sc[8192 + m*64 + so];
      }
#pragma unroll
      for (int nb = 0; nb < 2; ++nb) {
        int n = wcol*32 + nb*16 + l15;
        int so = (c ^ (n & 7))*8;
        bh_[nb] = *(const bf16x8*)&Sc[16384 + n*64 + so];
        bl_[nb] = *(const bf16x8*)&Sc[24576 + n*64 + so];
      }
#pragma unroll
      for (int mb = 0; mb < 4; ++mb)
#pragma unroll
        for (int nb = 0; nb < 2; ++nb) {
          acc[mb][nb] = __builtin_amdgcn_mfma_f32_16x16x32_bf16(ah[mb], bh_[nb], acc[mb][nb], 0,0,0);
          acc[mb][nb] = __builtin_amdgcn_mfma_f32_16x16x32_bf16(al[mb], bh_[nb], acc[mb][nb], 0,0,0);
          acc[mb][nb] = __builtin_amdgcn_mfma_f32_16x16x32_bf16(ah[mb], bl_[nb], acc[mb][nb], 0,0,0);
        }
    }
    __syncthreads();   // drains this wave's vmcnt; buffer swap safe
    cur ^= 1;
  }

  float bvv[2];
#pragma unroll
  for (int nb = 0; nb < 2; ++nb) bvv[nb] = bias[n0 + wcol*32 + nb*16 + l15];
#pragma unroll
  for (int mb = 0; mb < 4; ++mb)
#pragma unroll
    for (int r = 0; r < 4; ++r) {
      int m = m0 + wrow*64 + mb*16 + lq*4 + r;
#pragma unroll
      for (int nb = 0; nb < 2; ++nb) {
        int n = n0 + wcol*32 + nb*16 + l15;
        out[(size_t)m*1024 + n] = acc[mb][nb][r] + bvv[nb];
      }
    }
}

// ---------------------------------------------------------------------------
extern "C" void kernel_launch(void* const* d_in, const int* in_sizes, int n_in,
                              void* d_out, int out_size, void* d_ws, size_t ws_size,
                              hipStream_t stream)
{
  const float* x   = (const float*)d_in[0];
  const float* Wq  = (const float*)d_in[1];
  const float* bq  = (const float*)d_in[2];
  const float* Wk  = (const float*)d_in[3];
  const float* bk  = (const float*)d_in[4];
  const float* Wv  = (const float*)d_in[5];
  const float* bv  = (const float*)d_in[6];
  const float* Wo  = (const float*)d_in[7];
  const float* bo  = (const float*)d_in[8];
  const float* J   = (const float*)d_in[9];
  const float* lam = (const float*)d_in[10];

  // ws layout (~64 MB): split-K partials removed; build_qj2 fused away.
  char* p = (char*)d_ws;
  unsigned short* xh     = (unsigned short*)p;  p += (size_t)4096*1024*2;    //  8.39M
  unsigned short* wcat3  = (unsigned short*)p;  p += (size_t)3072*1024*2;    //  6.29M
  unsigned short* Jt     = (unsigned short*)p;  p += (size_t)16*64*64*2;     //  0.13M
  p += (size_t)2*1024*1024;                      // pad
  unsigned short* Qcat   = (unsigned short*)p;  p += (size_t)65536*128*2;    // 16.78M
  unsigned short* Kcat   = (unsigned short*)p;  p += (size_t)65536*128*2;    // 16.78M
  unsigned short* Vt     = (unsigned short*)p;  p += (size_t)32*64*2048*2;   //  8.39M
  unsigned short* wocat  = (unsigned short*)p;  p += (size_t)1024*2048*2;    //  4.19M
  unsigned short* attcat = (unsigned short*)p;  p += (size_t)4096*2048*2;    // 16.78M
  float* out = (float*)d_out;

  dim3 blk(256);

  prep_all<<<dim3(8208), blk, 0, stream>>>(x, Wq, Wk, Wv, Wo, J, lam, xh, wcat3, wocat, Jt);
  gemm_qkv<<<dim3(24, 32), blk, 0, stream>>>(xh, wcat3, bq, bk, bv, Jt, Qcat, Kcat, Vt);
  flash8<<<dim3(512), blk, 0, stream>>>(Qcat, Kcat, Vt, attcat);
  gemm3b<<<dim3(8, 32), dim3(512), 0, stream>>>(attcat, wocat, bo, out);
}

// Round 10
// 211.750 us; speedup vs baseline: 1.0442x; 1.0442x over previous
//
#include <hip/hip_runtime.h>
#include <math.h>

#define NH 16

typedef __bf16 bf16x8 __attribute__((ext_vector_type(8)));
typedef float f32x4 __attribute__((ext_vector_type(4)));

__device__ __forceinline__ unsigned short f2bf(float f) {
  unsigned u = __float_as_uint(f);
  u += 0x7fffu + ((u >> 16) & 1u);            // RNE (prep/epilogue paths only)
  return (unsigned short)(u >> 16);
}
__device__ __forceinline__ float bf2f(unsigned short h) {
  return __uint_as_float(((unsigned)h) << 16);
}
__device__ __forceinline__ float fexp2(float x) {
  return __builtin_amdgcn_exp2f(x);           // raw v_exp_f32 (2^x)
}
// Q is stored pre-scaled by 0.125*log2e. tanh(q) = 1 - 2/(2^(16*stored)+1).
__device__ __forceinline__ float fast_tanh16(float x) {
  return 1.f - 2.f * __builtin_amdgcn_rcpf(fexp2(16.f * x) + 1.f);
}
__device__ __forceinline__ void gl_lds16(const void* g, void* l) {
  __builtin_amdgcn_global_load_lds((const __attribute__((address_space(1))) void*)g,
                                   (__attribute__((address_space(3))) void*)l, 16, 0, 0);
}
union Frag8 { bf16x8 v; unsigned short u[8]; };
union FragU { bf16x8 v; unsigned u[4]; };

// ---------------------------------------------------------------------------
// prep_all: one launch for ALL input conversions (x, Wq/Wk/Wv, Wo split,
// and the lam*log2e*J^T transpose folded in as blocks 8192..8207).
// ---------------------------------------------------------------------------
__global__ __launch_bounds__(256) void prep_all(const float* __restrict__ x,
                                                const float* __restrict__ Wq,
                                                const float* __restrict__ Wk,
                                                const float* __restrict__ Wv,
                                                const float* __restrict__ Wo,
                                                const float* __restrict__ J,
                                                const float* __restrict__ lam_p,
                                                unsigned short* __restrict__ xh,
                                                unsigned short* __restrict__ wcat3,
                                                unsigned short* __restrict__ wocat,
                                                unsigned short* __restrict__ Jt)
{
  __shared__ float T[64][65];
  const int bid = blockIdx.x, tid = threadIdx.x;
  if (bid >= 8192) {
    // prep_jt: Jt[h][e][d] = bf16( lam * log2e * J[h][d][e] )
    const int h = bid - 8192;
    const float lam = lam_p[0] * 1.44269504f;
#pragma unroll
    for (int c = 0; c < 4; ++c) {
      int i = tid + c*256;
      int d = i >> 4, e4 = i & 15;
      float4 v = *(const float4*)&J[(size_t)h*4096 + d*64 + e4*4];
      T[d][e4*4+0] = v.x; T[d][e4*4+1] = v.y; T[d][e4*4+2] = v.z; T[d][e4*4+3] = v.w;
    }
    __syncthreads();
    const int e = tid >> 2, d0 = (tid & 3) * 16;
#pragma unroll
    for (int j4 = 0; j4 < 4; ++j4) {
      ushort4 o;
      o.x = f2bf(lam * T[d0+j4*4+0][e]);
      o.y = f2bf(lam * T[d0+j4*4+1][e]);
      o.z = f2bf(lam * T[d0+j4*4+2][e]);
      o.w = f2bf(lam * T[d0+j4*4+3][e]);
      *(ushort4*)&Jt[((size_t)h*64 + e)*64 + d0 + j4*4] = o;
    }
    return;
  }
  if (bid < 4096) {
    int i = bid * 256 + tid;
    float4 v = *(const float4*)&x[(size_t)i*4];
    ushort4 o;
    o.x = f2bf(v.x); o.y = f2bf(v.y); o.z = f2bf(v.z); o.w = f2bf(v.w);
    *(ushort4*)&xh[(size_t)i*4] = o;
  } else if (bid < 7168) {
    int i = (bid - 4096) * 256 + tid;
    int sel = i >> 18, loc = i & 262143;
    const float* src = (sel == 0) ? Wq : (sel == 1) ? Wk : Wv;
    float4 v = *(const float4*)&src[(size_t)loc*4];
    ushort4 o;
    o.x = f2bf(v.x); o.y = f2bf(v.y); o.z = f2bf(v.z); o.w = f2bf(v.w);
    *(ushort4*)&wcat3[(size_t)i*4] = o;
  } else {
    int i = (bid - 7168) * 256 + tid;
    int r = i >> 8, c = i & 255;
    float4 v = *(const float4*)&Wo[(size_t)r*1024 + c*4];
    ushort4 hi, lo;
    hi.x = f2bf(v.x); lo.x = f2bf(v.x - bf2f(hi.x));
    hi.y = f2bf(v.y); lo.y = f2bf(v.y - bf2f(hi.y));
    hi.z = f2bf(v.z); lo.z = f2bf(v.z - bf2f(hi.z));
    hi.w = f2bf(v.w); lo.w = f2bf(v.w - bf2f(hi.w));
    *(ushort4*)&wocat[(size_t)r*2048 + c*4]        = hi;
    *(ushort4*)&wocat[(size_t)r*2048 + 1024 + c*4] = lo;
  }
}

// ---------------------------------------------------------------------------
// gemm_qkv: merged Q/K/V projection, 1-term bf16, 128x128 tile, BK=64.
// 4-wave / 64x64-per-wave geometry, one-barrier issue-early double buffer.
// build_qj2 fused into the mode-0 epilogue. mode-2 stores Vt key-permuted.
// R10: grid axes SWAPPED to (m=x:32, n=y:24). XCD = linear_id % 8 and
// 32 % 8 == 0, so all 24 blocks sharing one A-row-panel now land on the
// SAME XCD -> A panels (largest re-read operand) become L2-resident
// per-XCD instead of being replicated into all 8 L2s.
// ---------------------------------------------------------------------------
__global__ __launch_bounds__(256) void gemm_qkv(const unsigned short* __restrict__ A,
                                                const unsigned short* __restrict__ W,
                                                const float* __restrict__ bq,
                                                const float* __restrict__ bk,
                                                const float* __restrict__ bv,
                                                const unsigned short* __restrict__ Jt,
                                                unsigned short* __restrict__ Qcat,
                                                unsigned short* __restrict__ Kcat,
                                                unsigned short* __restrict__ Vt)
{
  __shared__ unsigned short S[32768];   // 2 buf x (A 8192 | W 8192) shorts
  const int tid = threadIdx.x, lane = tid & 63, wq = tid >> 6;
  const int l15 = lane & 15, lq = lane >> 4;
  const int n0 = blockIdx.y * 128, m0 = blockIdx.x * 128;
  const int wr = (wq & 1) * 64, wc = (wq >> 1) * 64;
  const int mode = n0 >> 10;

  f32x4 acc[4][4];
#pragma unroll
  for (int mb = 0; mb < 4; ++mb)
#pragma unroll
    for (int nb = 0; nb < 4; ++nb) { f32x4 z = {0.f,0.f,0.f,0.f}; acc[mb][nb] = z; }

  const unsigned short* mat = (wq < 2) ? A : W;
  const int rbase = (wq < 2) ? m0 : n0;
  const int srow = lane >> 3, sslot = lane & 7;

  auto STAGE = [&](int buf, int k0) {
    unsigned short* lb = S + buf*16384 + (wq >> 1) * 8192;
#pragma unroll
    for (int t = 0; t < 8; ++t) {
      int row = (wq & 1) * 64 + t*8 + srow;
      int chunk = sslot ^ (row & 7);
      gl_lds16(mat + (size_t)(rbase + row)*1024 + k0 + chunk*8,
               lb + ((wq & 1) * 64 + t*8) * 64);
    }
  };

  int cur = 0;
  STAGE(0, 0);
  __syncthreads();

  for (int k0 = 0; k0 < 1024; k0 += 64) {
    if (k0 + 64 < 1024) STAGE(cur ^ 1, k0 + 64);
    const unsigned short* Sc = S + cur*16384;
#pragma unroll
    for (int kk = 0; kk < 2; ++kk) {
      int c = kk*4 + lq;
      bf16x8 af[4], bf_[4];
#pragma unroll
      for (int mb = 0; mb < 4; ++mb) {
        int m = wr + mb*16 + l15;
        af[mb] = *(const bf16x8*)&Sc[m*64 + (c ^ (m & 7))*8];
      }
#pragma unroll
      for (int nb = 0; nb < 4; ++nb) {
        int n = wc + nb*16 + l15;
        bf_[nb] = *(const bf16x8*)&Sc[8192 + n*64 + (c ^ (n & 7))*8];
      }
#pragma unroll
      for (int mb = 0; mb < 4; ++mb)
#pragma unroll
        for (int nb = 0; nb < 4; ++nb)
          acc[mb][nb] = __builtin_amdgcn_mfma_f32_16x16x32_bf16(af[mb], bf_[nb], acc[mb][nb], 0,0,0);
    }
    __syncthreads();   // drains prefetch vmcnt AFTER compute
    cur ^= 1;
  }

  const float* bias = (mode == 0) ? bq : (mode == 1) ? bk : bv;
  float bvv[4];
#pragma unroll
  for (int nb = 0; nb < 4; ++nb) bvv[nb] = bias[((n0 & 1023) + wc + nb*16 + l15)];

  if (mode == 2) {
#pragma unroll
    for (int mb = 0; mb < 4; ++mb) {
      int mrow = m0 + wr + mb*16 + lq*4;
      int b = mrow >> 11, s0 = mrow & 2047;
      // key-window permutation: group g=(s0>>2)&7 -> position 2*(g&3)+(g>>2)
      int s0p = (s0 & ~31) + (((s0 >> 2) & 3) << 3) + (((s0 >> 4) & 1) << 2);
#pragma unroll
      for (int nb = 0; nb < 4; ++nb) {
        int n = (n0 & 1023) + wc + nb*16 + l15;
        int h = n >> 6, d = n & 63;
        ushort4 o;
        o.x = f2bf(acc[mb][nb][0] + bvv[nb]);
        o.y = f2bf(acc[mb][nb][1] + bvv[nb]);
        o.z = f2bf(acc[mb][nb][2] + bvv[nb]);
        o.w = f2bf(acc[mb][nb][3] + bvv[nb]);
        *(ushort4*)&Vt[((size_t)(b*NH + h)*64 + d)*2048 + s0p] = o;
      }
    }
    return;
  }

  if (mode == 1) {
#pragma unroll
    for (int mb = 0; mb < 4; ++mb) {
#pragma unroll
      for (int r = 0; r < 4; ++r) {
        int m = m0 + wr + mb*16 + lq*4 + r;
        int b = m >> 11, s = m & 2047;
#pragma unroll
        for (int nb = 0; nb < 4; ++nb) {
          float v = acc[mb][nb][r] + bvv[nb];
          int n = (n0 & 1023) + wc + nb*16 + l15;
          int h = n >> 6, d = n & 63;
          size_t row = ((size_t)(b*NH + h)*2048 + s)*128;
          Kcat[row + d]      = f2bf(v);
          Kcat[row + 64 + d] = f2bf(1.f - 2.f * __builtin_amdgcn_rcpf(__expf(2.f*v) + 1.f));
        }
      }
    }
    return;
  }

  // ---- mode 0: Q write + fused QJ (formerly build_qj2) ----
  unsigned short* T = S + wq * 4608;
#pragma unroll
  for (int mb = 0; mb < 4; ++mb) {
#pragma unroll
    for (int r = 0; r < 4; ++r) {
      int m = m0 + wr + mb*16 + lq*4 + r;
      int b = m >> 11, s = m & 2047;
#pragma unroll
      for (int nb = 0; nb < 4; ++nb) {
        float v = acc[mb][nb][r] + bvv[nb];
        int n = (n0 & 1023) + wc + nb*16 + l15;
        int h = n >> 6, d = n & 63;
        unsigned short qb = f2bf(v * 0.18033688f);   // 0.125 * log2(e)
        Qcat[((size_t)(b*NH + h)*2048 + s)*128 + d] = qb;
        T[(mb*16 + lq*4 + r)*72 + d] = qb;
      }
    }
  }
  const int h = ((n0 & 1023) + wc) >> 6;             // this wave's head
  bf16x8 jf2[4][2];
#pragma unroll
  for (int nb2 = 0; nb2 < 4; ++nb2)
#pragma unroll
    for (int kst = 0; kst < 2; ++kst)
      jf2[nb2][kst] = *(const bf16x8*)&Jt[((size_t)h*64 + nb2*16 + l15)*64 + kst*32 + lq*8];
#pragma unroll
  for (int mb = 0; mb < 4; ++mb) {
    Frag8 af2[2];
#pragma unroll
    for (int kst = 0; kst < 2; ++kst) {
      Frag8 raw;
      raw.v = *(const bf16x8*)&T[(mb*16 + l15)*72 + kst*32 + lq*8];
#pragma unroll
      for (int j = 0; j < 8; ++j) {
        float t = fast_tanh16(bf2f(raw.u[j]));
        af2[kst].u[j] = (unsigned short)(__float_as_uint(t) >> 16);  // trunc
      }
    }
    f32x4 a2[4];
#pragma unroll
    for (int nb2 = 0; nb2 < 4; ++nb2) { f32x4 z = {0.f,0.f,0.f,0.f}; a2[nb2] = z; }
#pragma unroll
    for (int kst = 0; kst < 2; ++kst)
#pragma unroll
      for (int nb2 = 0; nb2 < 4; ++nb2)
        a2[nb2] = __builtin_amdgcn_mfma_f32_16x16x32_bf16(af2[kst].v, jf2[nb2][kst], a2[nb2], 0,0,0);
    int mrow = m0 + wr + mb*16 + lq*4;
    int b = mrow >> 11, s0 = mrow & 2047;
#pragma unroll
    for (int r = 0; r < 4; ++r) {
      size_t rowb = ((size_t)(b*NH + h)*2048 + s0 + r)*128 + 64;
#pragma unroll
      for (int nb2 = 0; nb2 < 4; ++nb2)
        Qcat[rowb + nb2*16 + l15] = f2bf(a2[nb2][r]);
    }
  }
}

// ---------------------------------------------------------------------------
// flash8: S^T MFMA flash, NO split-K. grid 512 (32 bh x 16 row-tiles),
// 256 thr / 4 waves, dbuf, __syncthreads schedule (R8 known-good).
// R9's counted-vmcnt regressed (+3.7%) — T4 needs the 8-phase interleave
// (regime gate, m218); at this structure the kernel sits AT the 2-barrier
// ceiling: 56 GF-equiv / 65us = ~860 TF = 34% MfmaUtil (matches counter).
// V read is a single ds_read_b128 (Vt key-permuted at write).
// ---------------------------------------------------------------------------
__global__ __launch_bounds__(256, 4) void flash8(
    const unsigned short* __restrict__ Qcat, const unsigned short* __restrict__ Kcat,
    const unsigned short* __restrict__ Vt, unsigned short* __restrict__ attcat)
{
  __shared__ __align__(16) char smem[49152];
  unsigned short* Ks = (unsigned short*)smem;            // 2 x 64x128 bf16
  unsigned short* Vs = (unsigned short*)(smem + 32768);  // 2 x 64x64  bf16
  const int tid = threadIdx.x, lane = tid & 63, wq = tid >> 6;
  const int l15 = lane & 15, lq = lane >> 4;
  const int bid = blockIdx.x;
  // bid = xcd + 8*(bhi + 4*inner): same bh -> same XCD L2
  const int bh = (((bid >> 3) & 3) << 3) | (bid & 7);
  const int inner = bid >> 5;                  // 0..15
  const int row0 = inner * 128;

  Frag8 qf[2][4];
#pragma unroll
  for (int nb = 0; nb < 2; ++nb) {
    const unsigned short* qp = Qcat + ((size_t)(bh*2048 + row0 + wq*32 + nb*16 + l15))*128 + lq*8;
#pragma unroll
    for (int kst = 0; kst < 4; ++kst)
      qf[nb][kst].v = *(const bf16x8*)(qp + kst*32);
  }

  FragU ones;
  ones.u[0] = 0x3F803F80u; ones.u[1] = 0x3F803F80u;
  ones.u[2] = 0x3F803F80u; ones.u[3] = 0x3F803F80u;

  f32x4 o[4][2];
  f32x4 lacc[2];
  { f32x4 z = {0.f,0.f,0.f,0.f}; lacc[0] = z; lacc[1] = z; }
#pragma unroll
  for (int db = 0; db < 4; ++db)
#pragma unroll
    for (int nb = 0; nb < 2; ++nb) { f32x4 z = {0.f,0.f,0.f,0.f}; o[db][nb] = z; }

  const unsigned short* kgb = Kcat + ((size_t)bh*2048)*128;
  const unsigned short* vg  = Vt + (size_t)bh*64*2048;

  auto STAGE = [&](int buf, int jt) {
#pragma unroll
    for (int t = 0; t < 4; ++t) {
      int g = (wq*4 + t)*4 + (lane >> 4);
      int slot = lane & 15;
      int chunk = (slot & 8) | ((slot ^ g) & 7);
      gl_lds16(kgb + (size_t)(jt*64 + g)*128 + chunk*8, Ks + buf*8192 + (wq*4 + t)*512);
    }
#pragma unroll
    for (int t = 0; t < 2; ++t) {
      int rv = (wq*2 + t)*8 + (lane >> 3);
      int chunk = (lane & 7) ^ (rv & 7);
      gl_lds16(vg + (size_t)rv*2048 + jt*64 + chunk*8, Vs + buf*4096 + (wq*2 + t)*512);
    }
  };

  int cur = 0;
  STAGE(0, 0);
  __syncthreads();

  for (int jt = 0; jt < 32; ++jt) {
    if (jt + 1 < 32) STAGE(cur ^ 1, jt + 1);
    const unsigned short* ksb = Ks + cur*8192;
    const unsigned short* vsb = Vs + cur*4096;

    // process keys in two half-tiles of 32: QK^T + exp then immediately PV,
    // so only 8 packed-P regs are live at a time.
#pragma unroll
    for (int t = 0; t < 2; ++t) {
      unsigned P2[2][2][2];
#pragma unroll
      for (int kk = 0; kk < 2; ++kk) {
        const int kb = 2*t + kk;
        bf16x8 af[4];
#pragma unroll
        for (int kst = 0; kst < 4; ++kst) {
          int key = kb*16 + l15;
          int c = kst*4 + lq;
          int slot = (c & 8) | ((c ^ key) & 7);
          af[kst] = *(const bf16x8*)&ksb[key*128 + slot*8];
        }
        f32x4 s[2];
        { f32x4 z = {0.f,0.f,0.f,0.f}; s[0] = z; s[1] = z; }
        __builtin_amdgcn_s_setprio(1);
#pragma unroll
        for (int kst = 0; kst < 4; ++kst) {
          s[0] = __builtin_amdgcn_mfma_f32_16x16x32_bf16(af[kst], qf[0][kst].v, s[0], 0,0,0);
          s[1] = __builtin_amdgcn_mfma_f32_16x16x32_bf16(af[kst], qf[1][kst].v, s[1], 0,0,0);
        }
        __builtin_amdgcn_s_setprio(0);
#pragma unroll
        for (int nb = 0; nb < 2; ++nb) {
          float e0 = fexp2(s[nb][0]), e1 = fexp2(s[nb][1]);
          float e2 = fexp2(s[nb][2]), e3 = fexp2(s[nb][3]);
          P2[nb][kk][0] = __builtin_amdgcn_perm(__float_as_uint(e1), __float_as_uint(e0), 0x07060302u);
          P2[nb][kk][1] = __builtin_amdgcn_perm(__float_as_uint(e3), __float_as_uint(e2), 0x07060302u);
        }
      }

      // PV for this half-tile (keys t*32 .. t*32+31)
      FragU bfr[2];
#pragma unroll
      for (int nb = 0; nb < 2; ++nb) {
        bfr[nb].u[0] = P2[nb][0][0];
        bfr[nb].u[1] = P2[nb][0][1];
        bfr[nb].u[2] = P2[nb][1][0];
        bfr[nb].u[3] = P2[nb][1][1];
      }
      __builtin_amdgcn_s_setprio(1);
      // row-sum of P over these 32 keys via ones-MFMA (D rows all = col sum)
      lacc[0] = __builtin_amdgcn_mfma_f32_16x16x32_bf16(ones.v, bfr[0].v, lacc[0], 0,0,0);
      lacc[1] = __builtin_amdgcn_mfma_f32_16x16x32_bf16(ones.v, bfr[1].v, lacc[1], 0,0,0);

#pragma unroll
      for (int db = 0; db < 4; ++db) {
        int d = db*16 + l15;
        Frag8 va;
        va.v = *(const bf16x8*)&vsb[d*64 + (((4*t + lq) ^ (d & 7)) * 8)];
        o[db][0] = __builtin_amdgcn_mfma_f32_16x16x32_bf16(va.v, bfr[0].v, o[db][0], 0,0,0);
        o[db][1] = __builtin_amdgcn_mfma_f32_16x16x32_bf16(va.v, bfr[1].v, o[db][1], 0,0,0);
      }
      __builtin_amdgcn_s_setprio(0);
    }

    __syncthreads();   // drains prefetch vmcnt AFTER compute
    cur ^= 1;
  }

  // epilogue: divide by denominator (lacc rows identical, per-lane by q=l15),
  // write attcat bf16 hi|lo directly, coalesced via LDS transpose (two halves
  // of 64 rows; Ts overlays the dead Ks/Vs).
  const int b = bh >> 4, h = bh & (NH-1);
  const float inv0 = 1.f / lacc[0][0];
  const float inv1 = 1.f / lacc[1][0];
  float* Ts = (float*)smem;                    // 64 x 65 f32 = 16.6KB
#pragma unroll
  for (int half = 0; half < 2; ++half) {
    __syncthreads();
    if ((wq >> 1) == half) {
#pragma unroll
      for (int nb = 0; nb < 2; ++nb) {
        const float inv = nb ? inv1 : inv0;
        const int rl = (wq & 1)*32 + nb*16 + l15;
#pragma unroll
        for (int db = 0; db < 4; ++db)
#pragma unroll
          for (int r = 0; r < 4; ++r)
            Ts[rl*65 + db*16 + lq*4 + r] = o[db][nb][r] * inv;
      }
    }
    __syncthreads();
    const int sl = tid >> 2, d0 = (tid & 3) * 16;
    const int srow = row0 + half*64 + sl;
    const size_t rb = ((size_t)(b*2048 + srow))*2048 + h*64;
#pragma unroll
    for (int j4 = 0; j4 < 4; ++j4) {
      float v0 = Ts[sl*65 + d0 + j4*4 + 0];
      float v1 = Ts[sl*65 + d0 + j4*4 + 1];
      float v2 = Ts[sl*65 + d0 + j4*4 + 2];
      float v3 = Ts[sl*65 + d0 + j4*4 + 3];
      ushort4 hi, lo;
      hi.x = f2bf(v0); lo.x = f2bf(v0 - bf2f(hi.x));
      hi.y = f2bf(v1); lo.y = f2bf(v1 - bf2f(hi.y));
      hi.z = f2bf(v2); lo.z = f2bf(v2 - bf2f(hi.z));
      hi.w = f2bf(v3); lo.w = f2bf(v3 - bf2f(hi.w));
      *(ushort4*)&attcat[rb + d0 + j4*4]        = hi;
      *(ushort4*)&attcat[rb + 1024 + d0 + j4*4] = lo;
    }
  }
}

// ---------------------------------------------------------------------------
// gemm3b: out = attn@Wo^T + bo, split-bf16 3-term.
// 128x128 tile, 8 waves (512 thr), grid 256 blocks = exactly 1/CU.
// R10: grid axes swapped (m=x:32, n=y:8; 32%8==0) -> same-attcat-panel
// blocks co-XCD (attcat is the 16.8MB re-read operand).
// ---------------------------------------------------------------------------
__global__ __launch_bounds__(512) void gemm3b(const unsigned short* __restrict__ A,
                                              const unsigned short* __restrict__ W,
                                              const float* __restrict__ bias,
                                              float* __restrict__ out)
{
  __shared__ unsigned short S[65536];   // 2 buffers x 4 regions x 128x64
  const int tid = threadIdx.x, lane = tid & 63, wid = tid >> 6;
  const int l15 = lane & 15, lq = lane >> 4;
  const int n0 = blockIdx.y * 128, m0 = blockIdx.x * 128;
  const int wrow = wid >> 2, wcol = wid & 3;     // 2x4 wave grid, 64x32 each

  f32x4 acc[4][2];
#pragma unroll
  for (int mb = 0; mb < 4; ++mb)
#pragma unroll
    for (int nb = 0; nb < 2; ++nb) { f32x4 z = {0.f,0.f,0.f,0.f}; acc[mb][nb] = z; }

  // staging: region = wid>>1 (0=A-hi,1=A-lo,2=W-hi,3=W-lo), each wave 64 rows
  const int region = wid >> 1;
  const unsigned short* mat = (region < 2) ? A : W;
  const int rbase = (region < 2) ? m0 : n0;
  const int koff  = (region & 1) * 1024;
  const int rhalf = (wid & 1) * 64;
  const int srow = lane >> 3, sslot = lane & 7;

  auto STAGE = [&](int buf, int k0) {
    unsigned short* lb = S + buf*32768 + region*8192 + rhalf*64;
#pragma unroll
    for (int t = 0; t < 8; ++t) {
      int row = rhalf + t*8 + srow;
      int chunk = sslot ^ (row & 7);
      gl_lds16(mat + (size_t)(rbase + row)*2048 + koff + k0 + chunk*8,
               lb + t*512);
    }
  };

  int cur = 0;
  STAGE(0, 0);
  __syncthreads();

  for (int k0 = 0; k0 < 1024; k0 += 64) {
    if (k0 + 64 < 1024) STAGE(cur ^ 1, k0 + 64);
    const unsigned short* Sc = S + cur*32768;
#pragma unroll
    for (int kk = 0; kk < 2; ++kk) {
      int c = kk*4 + lq;
      bf16x8 ah[4], al[4], bh_[2], bl_[2];
#pragma unroll
      for (int mb = 0; mb < 4; ++mb) {
        int m = wrow*64 + mb*16 + l15;
        int so = (c ^ (m & 7))*8;
        ah[mb] = *(const bf16x8*)&Sc[m*64 + so];
        al[mb] = *(const bf16x8*)&Sc[8192 + m*64 + so];
      }
#pragma unroll
      for (int nb = 0; nb < 2; ++nb) {
        int n = wcol*32 + nb*16 + l15;
        int so = (c ^ (n & 7))*8;
        bh_[nb] = *(const bf16x8*)&Sc[16384 + n*64 + so];
        bl_[nb] = *(const bf16x8*)&Sc[24576 + n*64 + so];
      }
#pragma unroll
      for (int mb = 0; mb < 4; ++mb)
#pragma unroll
        for (int nb = 0; nb < 2; ++nb) {
          acc[mb][nb] = __builtin_amdgcn_mfma_f32_16x16x32_bf16(ah[mb], bh_[nb], acc[mb][nb], 0,0,0);
          acc[mb][nb] = __builtin_amdgcn_mfma_f32_16x16x32_bf16(al[mb], bh_[nb], acc[mb][nb], 0,0,0);
          acc[mb][nb] = __builtin_amdgcn_mfma_f32_16x16x32_bf16(ah[mb], bl_[nb], acc[mb][nb], 0,0,0);
        }
    }
    __syncthreads();   // drains this wave's vmcnt; buffer swap safe
    cur ^= 1;
  }

  float bvv[2];
#pragma unroll
  for (int nb = 0; nb < 2; ++nb) bvv[nb] = bias[n0 + wcol*32 + nb*16 + l15];
#pragma unroll
  for (int mb = 0; mb < 4; ++mb)
#pragma unroll
    for (int r = 0; r < 4; ++r) {
      int m = m0 + wrow*64 + mb*16 + lq*4 + r;
#pragma unroll
      for (int nb = 0; nb < 2; ++nb) {
        int n = n0 + wcol*32 + nb*16 + l15;
        out[(size_t)m*1024 + n] = acc[mb][nb][r] + bvv[nb];
      }
    }
}

// ---------------------------------------------------------------------------
extern "C" void kernel_launch(void* const* d_in, const int* in_sizes, int n_in,
                              void* d_out, int out_size, void* d_ws, size_t ws_size,
                              hipStream_t stream)
{
  const float* x   = (const float*)d_in[0];
  const float* Wq  = (const float*)d_in[1];
  const float* bq  = (const float*)d_in[2];
  const float* Wk  = (const float*)d_in[3];
  const float* bk  = (const float*)d_in[4];
  const float* Wv  = (const float*)d_in[5];
  const float* bv  = (const float*)d_in[6];
  const float* Wo  = (const float*)d_in[7];
  const float* bo  = (const float*)d_in[8];
  const float* J   = (const float*)d_in[9];
  const float* lam = (const float*)d_in[10];

  // ws layout (~64 MB): split-K partials removed; build_qj2 fused away.
  char* p = (char*)d_ws;
  unsigned short* xh     = (unsigned short*)p;  p += (size_t)4096*1024*2;    //  8.39M
  unsigned short* wcat3  = (unsigned short*)p;  p += (size_t)3072*1024*2;    //  6.29M
  unsigned short* Jt     = (unsigned short*)p;  p += (size_t)16*64*64*2;     //  0.13M
  p += (size_t)2*1024*1024;                      // pad
  unsigned short* Qcat   = (unsigned short*)p;  p += (size_t)65536*128*2;    // 16.78M
  unsigned short* Kcat   = (unsigned short*)p;  p += (size_t)65536*128*2;    // 16.78M
  unsigned short* Vt     = (unsigned short*)p;  p += (size_t)32*64*2048*2;   //  8.39M
  unsigned short* wocat  = (unsigned short*)p;  p += (size_t)1024*2048*2;    //  4.19M
  unsigned short* attcat = (unsigned short*)p;  p += (size_t)4096*2048*2;    // 16.78M
  float* out = (float*)d_out;

  dim3 blk(256);

  prep_all<<<dim3(8208), blk, 0, stream>>>(x, Wq, Wk, Wv, Wo, J, lam, xh, wcat3, wocat, Jt);
  gemm_qkv<<<dim3(32, 24), blk, 0, stream>>>(xh, wcat3, bq, bk, bv, Jt, Qcat, Kcat, Vt);
  flash8<<<dim3(512), blk, 0, stream>>>(Qcat, Kcat, Vt, attcat);
  gemm3b<<<dim3(32, 8), dim3(512), 0, stream>>>(attcat, wocat, bo, out);
}